// Round 1
// baseline (483.588 us; speedup 1.0000x reference)
//
#include <hip/hip_runtime.h>
#include <stdint.h>

#define NBINS 256
#define HW_SHIFT 20            // h*w = 1024*1024 = 1<<20
#define HW4_SHIFT (HW_SHIFT-2) // float4 per image = 1<<18
#define BLK_PER_IMG 64

__device__ __forceinline__ unsigned enc_f(float f) {
    unsigned u = __float_as_uint(f);
    return (u & 0x80000000u) ? ~u : (u | 0x80000000u);
}
__device__ __forceinline__ float dec_f(unsigned e) {
    unsigned u = (e & 0x80000000u) ? (e ^ 0x80000000u) : ~e;
    return __uint_as_float(u);
}

// ws layout: [0]=min_enc, [1]=max_enc, [2..2+nimg*256)=hist, then thresh[nimg]
__global__ void k_init(unsigned* mmo, unsigned* hist, int nhist) {
    int t = threadIdx.x + blockIdx.x * blockDim.x;
    if (t == 0) { mmo[0] = 0xFFFFFFFFu; mmo[1] = 0u; }
    for (int i = t; i < nhist; i += blockDim.x * gridDim.x) hist[i] = 0u;
}

__global__ void k_minmax(const float4* __restrict__ x, unsigned* mmo, long n4) {
    unsigned mn = 0xFFFFFFFFu, mx = 0u;
    long stride = (long)gridDim.x * blockDim.x;
    for (long i = (long)blockIdx.x * blockDim.x + threadIdx.x; i < n4; i += stride) {
        float4 v = x[i];
        unsigned e0 = enc_f(v.x), e1 = enc_f(v.y), e2 = enc_f(v.z), e3 = enc_f(v.w);
        mn = min(mn, min(min(e0, e1), min(e2, e3)));
        mx = max(mx, max(max(e0, e1), max(e2, e3)));
    }
    for (int off = 32; off > 0; off >>= 1) {
        mn = min(mn, (unsigned)__shfl_down((int)mn, off));
        mx = max(mx, (unsigned)__shfl_down((int)mx, off));
    }
    __shared__ unsigned smn[4], smx[4];
    int lane = threadIdx.x & 63, w = threadIdx.x >> 6;
    if (lane == 0) { smn[w] = mn; smx[w] = mx; }
    __syncthreads();
    if (threadIdx.x == 0) {
        for (int j = 1; j < (int)(blockDim.x >> 6); j++) {
            mn = min(mn, smn[j]); mx = max(mx, smx[j]);
        }
        atomicMin(&mmo[0], mn);
        atomicMax(&mmo[1], mx);
    }
}

__global__ void k_hist(const float4* __restrict__ x, const unsigned* __restrict__ mmo,
                       unsigned* __restrict__ ghist) {
    __shared__ unsigned sh[NBINS];
    for (int i = threadIdx.x; i < NBINS; i += blockDim.x) sh[i] = 0u;
    __syncthreads();
    float mn = dec_f(mmo[0]);
    float mx = dec_f(mmo[1]);
    float span = mx - mn;                    // fp32 sub, matches np
    float scale = __fdiv_rn(256.0f, span);   // NBINS/span in fp32
    int img = blockIdx.x / BLK_PER_IMG;
    int blk = blockIdx.x % BLK_PER_IMG;
    const float4* base = x + ((long)img << HW4_SHIFT);
    const int n4i = 1 << HW4_SHIFT;
    for (int i = blk * blockDim.x + threadIdx.x; i < n4i; i += BLK_PER_IMG * blockDim.x) {
        float4 v = base[i];
        // (x - mn) * scale : sub then mul, no fma contraction possible
        int b0 = (int)floorf((v.x - mn) * scale);
        int b1 = (int)floorf((v.y - mn) * scale);
        int b2 = (int)floorf((v.z - mn) * scale);
        int b3 = (int)floorf((v.w - mn) * scale);
        b0 = min(max(b0, 0), NBINS - 1);
        b1 = min(max(b1, 0), NBINS - 1);
        b2 = min(max(b2, 0), NBINS - 1);
        b3 = min(max(b3, 0), NBINS - 1);
        atomicAdd(&sh[b0], 1u);
        atomicAdd(&sh[b1], 1u);
        atomicAdd(&sh[b2], 1u);
        atomicAdd(&sh[b3], 1u);
    }
    __syncthreads();
    for (int i = threadIdx.x; i < NBINS; i += blockDim.x) {
        unsigned c = sh[i];
        if (c) atomicAdd(&ghist[img * NBINS + i], c);
    }
}

// One thread per image: sequential cumsums exactly mirror np.cumsum order.
__global__ void k_otsu(const unsigned* __restrict__ ghist, const unsigned* __restrict__ mmo,
                       float* __restrict__ thresh, int nimg) {
    int i = threadIdx.x + blockIdx.x * blockDim.x;
    if (i >= nimg) return;
    const unsigned* h = ghist + i * NBINS;
    const float inv_total = 1.0f / 1048576.0f; // exact 2^-20; counts <= 2^20 so p is exact
    // pass 1: total = s_bg[255], accumulated in the same order as pass 2
    float w = 0.0f, s = 0.0f;
    for (int t = 0; t < NBINS; t++) {
        float p = __fmul_rn((float)h[t], inv_total);
        w = __fadd_rn(w, p);
        s = __fadd_rn(s, __fmul_rn(p, (float)t));
    }
    float total = s;
    // pass 2: running cumsum + var argmax (strict > keeps first index, like np.argmax)
    float best = -__builtin_inff();
    int bestt = 0;
    w = 0.0f; s = 0.0f;
    for (int t = 0; t < NBINS; t++) {
        float p = __fmul_rn((float)h[t], inv_total);
        w = __fadd_rn(w, p);
        s = __fadd_rn(s, __fmul_rn(p, (float)t));
        float wf = __fsub_rn(1.0f, w);
        float var;
        if (w > 0.0f && wf > 0.0f) {
            float mb = __fdiv_rn(s, w);
            float mf = __fdiv_rn(__fsub_rn(total, s), wf);
            float d = __fsub_rn(mb, mf);
            var = __fmul_rn(__fmul_rn(w, wf), __fmul_rn(d, d));
        } else {
            var = -__builtin_inff();
        }
        if (var > best) { best = var; bestt = t; }
    }
    float mn = dec_f(mmo[0]);
    float mx = dec_f(mmo[1]);
    float span = __fsub_rn(mx, mn);
    float q = __fmul_rn((float)(bestt + 1), 1.0f / 256.0f); // exact (pow2)
    thresh[i] = __fadd_rn(mn, __fmul_rn(span, q));          // mul then add, no fma
}

__global__ void k_apply(const float4* __restrict__ x, float4* __restrict__ out,
                        const float* __restrict__ thresh, long n4) {
    long stride = (long)gridDim.x * blockDim.x;
    for (long i = (long)blockIdx.x * blockDim.x + threadIdx.x; i < n4; i += stride) {
        int img = (int)(i >> HW4_SHIFT); // wave-uniform (256 consecutive floats per wave)
        float th = thresh[img];
        float4 v = x[i];
        float4 o;
        o.x = (v.x <= th) ? 0.0f : v.x;
        o.y = (v.y <= th) ? 0.0f : v.y;
        o.z = (v.z <= th) ? 0.0f : v.z;
        o.w = (v.w <= th) ? 0.0f : v.w;
        out[i] = o;
    }
}

extern "C" void kernel_launch(void* const* d_in, const int* in_sizes, int n_in,
                              void* d_out, int out_size, void* d_ws, size_t ws_size,
                              hipStream_t stream) {
    const float* x = (const float*)d_in[0];
    float* out = (float*)d_out;
    long n = (long)in_sizes[0];          // 48 * 2^20
    long n4 = n >> 2;
    int nimg = (int)(n >> HW_SHIFT);     // 48

    unsigned* mmo = (unsigned*)d_ws;
    unsigned* ghist = mmo + 2;
    float* thresh = (float*)(ghist + nimg * NBINS);

    k_init<<<48, 256, 0, stream>>>(mmo, ghist, nimg * NBINS);
    k_minmax<<<2048, 256, 0, stream>>>((const float4*)x, mmo, n4);
    k_hist<<<nimg * BLK_PER_IMG, 256, 0, stream>>>((const float4*)x, mmo, ghist);
    k_otsu<<<1, 64, 0, stream>>>(ghist, mmo, thresh, nimg);
    k_apply<<<4096, 256, 0, stream>>>((const float4*)x, (float4*)out, thresh, n4);
}

// Round 3
// 476.667 us; speedup vs baseline: 1.0145x; 1.0145x over previous
//
#include <hip/hip_runtime.h>
#include <stdint.h>

#define NBINS 256
#define HW_SHIFT 20            // h*w = 1024*1024 = 1<<20
#define HW4_SHIFT (HW_SHIFT-2) // float4 per image = 1<<18
#define BLK_PER_IMG 64
#define NCOPY 32               // replicated LDS histograms, one per bank

typedef float nfloat4 __attribute__((ext_vector_type(4))); // clang vector: NT-store OK

__device__ __forceinline__ unsigned enc_f(float f) {
    unsigned u = __float_as_uint(f);
    // enc = u ^ ((int)u>>31 | 0x80000000): monotone order-preserving map
    return u ^ ((unsigned)((int)u >> 31) | 0x80000000u);
}
__device__ __forceinline__ float dec_f(unsigned e) {
    unsigned u = (e & 0x80000000u) ? (e ^ 0x80000000u) : ~e;
    return __uint_as_float(u);
}

// ws layout: [0]=min_enc, [1]=max_enc, [2..2+nimg*256)=hist, then thresh[nimg]
__global__ void k_init(unsigned* mmo, unsigned* hist, int nhist) {
    int t = threadIdx.x + blockIdx.x * blockDim.x;
    if (t == 0) { mmo[0] = 0xFFFFFFFFu; mmo[1] = 0u; }
    for (int i = t; i < nhist; i += blockDim.x * gridDim.x) hist[i] = 0u;
}

__global__ void k_minmax(const float4* __restrict__ x, unsigned* mmo, long n4) {
    unsigned mn = 0xFFFFFFFFu, mx = 0u;
    long stride = (long)gridDim.x * blockDim.x;
    for (long i = (long)blockIdx.x * blockDim.x + threadIdx.x; i < n4; i += stride) {
        float4 v = x[i];
        unsigned e0 = enc_f(v.x), e1 = enc_f(v.y), e2 = enc_f(v.z), e3 = enc_f(v.w);
        mn = min(mn, min(min(e0, e1), min(e2, e3)));
        mx = max(mx, max(max(e0, e1), max(e2, e3)));
    }
    for (int off = 32; off > 0; off >>= 1) {
        mn = min(mn, (unsigned)__shfl_down((int)mn, off));
        mx = max(mx, (unsigned)__shfl_down((int)mx, off));
    }
    __shared__ unsigned smn[4], smx[4];
    int lane = threadIdx.x & 63, w = threadIdx.x >> 6;
    if (lane == 0) { smn[w] = mn; smx[w] = mx; }
    __syncthreads();
    if (threadIdx.x == 0) {
        for (int j = 1; j < (int)(blockDim.x >> 6); j++) {
            mn = min(mn, smn[j]); mx = max(mx, smx[j]);
        }
        atomicMin(&mmo[0], mn);
        atomicMax(&mmo[1], mx);
    }
}

__global__ void k_hist(const float4* __restrict__ x, const unsigned* __restrict__ mmo,
                       unsigned* __restrict__ ghist) {
    // 32 bank-aligned histogram copies: copy c occupies only bank c.
    // sh[bin*32 + c], bank = c. Within a wave, lanes L and L+32 share copy
    // (2 lanes/bank = wave64 minimum, free per m136); cross-wave races use atomics.
    __shared__ unsigned sh[NBINS * NCOPY]; // 32 KB -> 5 blocks/CU, 20 waves/CU
    for (int i = threadIdx.x; i < NBINS * NCOPY; i += blockDim.x) sh[i] = 0u;
    __syncthreads();
    float mn = dec_f(mmo[0]);
    float mx = dec_f(mmo[1]);
    float span = mx - mn;                    // fp32 sub, matches np
    float scale = __fdiv_rn(256.0f, span);   // NBINS/span in fp32
    int img = blockIdx.x / BLK_PER_IMG;
    int blk = blockIdx.x % BLK_PER_IMG;
    const float4* base = x + ((long)img << HW4_SHIFT);
    const int n4i = 1 << HW4_SHIFT;
    int c = threadIdx.x & (NCOPY - 1);
    for (int i = blk * blockDim.x + threadIdx.x; i < n4i; i += BLK_PER_IMG * blockDim.x) {
        float4 v = base[i];
        // (x - mn) * scale : sub then mul, no fma contraction possible
        int b0 = (int)floorf((v.x - mn) * scale);
        int b1 = (int)floorf((v.y - mn) * scale);
        int b2 = (int)floorf((v.z - mn) * scale);
        int b3 = (int)floorf((v.w - mn) * scale);
        b0 = min(max(b0, 0), NBINS - 1);
        b1 = min(max(b1, 0), NBINS - 1);
        b2 = min(max(b2, 0), NBINS - 1);
        b3 = min(max(b3, 0), NBINS - 1);
        atomicAdd(&sh[b0 * NCOPY + c], 1u);
        atomicAdd(&sh[b1 * NCOPY + c], 1u);
        atomicAdd(&sh[b2 * NCOPY + c], 1u);
        atomicAdd(&sh[b3 * NCOPY + c], 1u);
    }
    __syncthreads();
    // Reduce the 32 copies. blockDim == 256 == NBINS: thread t owns bin t.
    // Staggered copy index (k+t)&31 keeps 2 lanes/bank (conflict-free).
    int bin = threadIdx.x;
    unsigned sum = 0;
    #pragma unroll
    for (int k = 0; k < NCOPY; k++) {
        int cc = (k + threadIdx.x) & (NCOPY - 1);
        sum += sh[bin * NCOPY + cc];
    }
    if (sum) atomicAdd(&ghist[img * NBINS + bin], sum);
}

// One thread per image; hist staged in padded LDS (stride 257 breaks the
// 48-way bank conflict of stride-256). Sequential cumsums mirror np.cumsum.
__global__ void k_otsu(const unsigned* __restrict__ ghist, const unsigned* __restrict__ mmo,
                       float* __restrict__ thresh, int nimg) {
    __shared__ unsigned sh[48 * (NBINS + 1)];
    int total_h = nimg * NBINS;
    for (int i = threadIdx.x; i < total_h; i += blockDim.x) {
        int im = i >> 8, b = i & 255;
        sh[im * (NBINS + 1) + b] = ghist[i];
    }
    __syncthreads();
    int i = threadIdx.x;
    if (i >= nimg) return;
    const unsigned* h = sh + i * (NBINS + 1);
    const float inv_total = 1.0f / 1048576.0f; // exact 2^-20; counts <= 2^20 so p is exact
    float w = 0.0f, s = 0.0f;
    for (int t = 0; t < NBINS; t++) {
        float p = __fmul_rn((float)h[t], inv_total);
        w = __fadd_rn(w, p);
        s = __fadd_rn(s, __fmul_rn(p, (float)t));
    }
    float total = s;
    float best = -__builtin_inff();
    int bestt = 0;
    w = 0.0f; s = 0.0f;
    for (int t = 0; t < NBINS; t++) {
        float p = __fmul_rn((float)h[t], inv_total);
        w = __fadd_rn(w, p);
        s = __fadd_rn(s, __fmul_rn(p, (float)t));
        float wf = __fsub_rn(1.0f, w);
        float var;
        if (w > 0.0f && wf > 0.0f) {
            float mb = __fdiv_rn(s, w);
            float mf = __fdiv_rn(__fsub_rn(total, s), wf);
            float d = __fsub_rn(mb, mf);
            var = __fmul_rn(__fmul_rn(w, wf), __fmul_rn(d, d));
        } else {
            var = -__builtin_inff();
        }
        if (var > best) { best = var; bestt = t; }
    }
    float mn = dec_f(mmo[0]);
    float mx = dec_f(mmo[1]);
    float span = __fsub_rn(mx, mn);
    float q = __fmul_rn((float)(bestt + 1), 1.0f / 256.0f); // exact (pow2)
    thresh[i] = __fadd_rn(mn, __fmul_rn(span, q));          // mul then add, no fma
}

__global__ void k_apply(const float4* __restrict__ x, nfloat4* __restrict__ out,
                        const float* __restrict__ thresh, long n4) {
    long stride = (long)gridDim.x * blockDim.x;
    for (long i = (long)blockIdx.x * blockDim.x + threadIdx.x; i < n4; i += stride) {
        int img = (int)(i >> HW4_SHIFT); // wave-uniform (256 consecutive floats per wave)
        float th = thresh[img];
        float4 v = x[i];
        nfloat4 o;
        o.x = (v.x <= th) ? 0.0f : v.x;
        o.y = (v.y <= th) ? 0.0f : v.y;
        o.z = (v.z <= th) ? 0.0f : v.z;
        o.w = (v.w <= th) ? 0.0f : v.w;
        // NT store: don't evict x from L3 with the output stream
        __builtin_nontemporal_store(o, &out[i]);
    }
}

extern "C" void kernel_launch(void* const* d_in, const int* in_sizes, int n_in,
                              void* d_out, int out_size, void* d_ws, size_t ws_size,
                              hipStream_t stream) {
    const float* x = (const float*)d_in[0];
    float* out = (float*)d_out;
    long n = (long)in_sizes[0];          // 48 * 2^20
    long n4 = n >> 2;
    int nimg = (int)(n >> HW_SHIFT);     // 48

    unsigned* mmo = (unsigned*)d_ws;
    unsigned* ghist = mmo + 2;
    float* thresh = (float*)(ghist + nimg * NBINS);

    k_init<<<48, 256, 0, stream>>>(mmo, ghist, nimg * NBINS);
    k_minmax<<<2048, 256, 0, stream>>>((const float4*)x, mmo, n4);
    k_hist<<<nimg * BLK_PER_IMG, 256, 0, stream>>>((const float4*)x, mmo, ghist);
    k_otsu<<<1, 256, 0, stream>>>(ghist, mmo, thresh, nimg);
    k_apply<<<4096, 256, 0, stream>>>((const float4*)x, (nfloat4*)out, thresh, n4);
}

// Round 4
// 439.762 us; speedup vs baseline: 1.0997x; 1.0839x over previous
//
#include <hip/hip_runtime.h>
#include <stdint.h>

#define NBINS 256
#define HW_SHIFT 20            // h*w = 1024*1024 = 1<<20
#define HW4_SHIFT (HW_SHIFT-2) // float4 per image = 1<<18
#define BLK_PER_IMG 32         // hist blocks per image
#define NCOPY 32               // replicated LDS histograms, one per bank
#define MM_BLOCKS 1024         // minmax blocks

typedef float nfloat4 __attribute__((ext_vector_type(4))); // clang vector: NT-store OK

__device__ __forceinline__ unsigned enc_f(float f) {
    unsigned u = __float_as_uint(f);
    return u ^ ((unsigned)((int)u >> 31) | 0x80000000u); // order-preserving monotone map
}
__device__ __forceinline__ float dec_f(unsigned e) {
    unsigned u = (e & 0x80000000u) ? (e ^ 0x80000000u) : ~e;
    return __uint_as_float(u);
}

// ws layout (every slot written unconditionally -> no init kernel needed):
//   [0 .. 2*MM_BLOCKS)                      per-block {mn,mx} pairs
//   [2*MM_BLOCKS .. +2)                     global {mn,mx} (k_reduce)
//   [.. + nimg*BLK_PER_IMG*NBINS)           partial histograms
//   [.. + nimg)                             thresholds (float)

__global__ void k_minmax(const float4* __restrict__ x, unsigned* __restrict__ bmm, long n4) {
    unsigned mn = 0xFFFFFFFFu, mx = 0u;
    long stride = (long)gridDim.x * blockDim.x;
    for (long i = (long)blockIdx.x * blockDim.x + threadIdx.x; i < n4; i += stride) {
        float4 v = x[i];
        unsigned e0 = enc_f(v.x), e1 = enc_f(v.y), e2 = enc_f(v.z), e3 = enc_f(v.w);
        mn = min(mn, min(min(e0, e1), min(e2, e3)));
        mx = max(mx, max(max(e0, e1), max(e2, e3)));
    }
    for (int off = 32; off > 0; off >>= 1) {
        mn = min(mn, (unsigned)__shfl_down((int)mn, off));
        mx = max(mx, (unsigned)__shfl_down((int)mx, off));
    }
    __shared__ unsigned smn[4], smx[4];
    int lane = threadIdx.x & 63, w = threadIdx.x >> 6;
    if (lane == 0) { smn[w] = mn; smx[w] = mx; }
    __syncthreads();
    if (threadIdx.x == 0) {
        for (int j = 1; j < (int)(blockDim.x >> 6); j++) {
            mn = min(mn, smn[j]); mx = max(mx, smx[j]);
        }
        bmm[2 * blockIdx.x]     = mn;
        bmm[2 * blockIdx.x + 1] = mx;
    }
}

__global__ void k_reduce(const unsigned* __restrict__ bmm, unsigned* __restrict__ mmo) {
    unsigned mn = 0xFFFFFFFFu, mx = 0u;
    for (int i = threadIdx.x; i < MM_BLOCKS; i += blockDim.x) {
        mn = min(mn, bmm[2 * i]);
        mx = max(mx, bmm[2 * i + 1]);
    }
    for (int off = 32; off > 0; off >>= 1) {
        mn = min(mn, (unsigned)__shfl_down((int)mn, off));
        mx = max(mx, (unsigned)__shfl_down((int)mx, off));
    }
    __shared__ unsigned smn[4], smx[4];
    int lane = threadIdx.x & 63, w = threadIdx.x >> 6;
    if (lane == 0) { smn[w] = mn; smx[w] = mx; }
    __syncthreads();
    if (threadIdx.x == 0) {
        for (int j = 1; j < (int)(blockDim.x >> 6); j++) {
            mn = min(mn, smn[j]); mx = max(mx, smx[j]);
        }
        mmo[0] = mn; mmo[1] = mx;
    }
}

__global__ void k_hist(const float4* __restrict__ x, const unsigned* __restrict__ mmo,
                       unsigned* __restrict__ partial) {
    // 32 bank-aligned histogram copies: copy c occupies only bank c.
    // Lanes L and L+32 share a copy (2 lanes/bank = wave64 minimum, free per m136).
    __shared__ unsigned sh[NBINS * NCOPY]; // 32 KB
    for (int i = threadIdx.x; i < NBINS * NCOPY; i += blockDim.x) sh[i] = 0u;
    __syncthreads();
    float mn = dec_f(mmo[0]);
    float mx = dec_f(mmo[1]);
    float span = mx - mn;                    // fp32 sub, matches np
    float scale = __fdiv_rn(256.0f, span);   // NBINS/span in fp32
    int img = blockIdx.x / BLK_PER_IMG;
    int blk = blockIdx.x % BLK_PER_IMG;
    const int chunk = (1 << HW4_SHIFT) / BLK_PER_IMG; // 8192 float4
    const float4* base = x + ((long)img << HW4_SHIFT) + (long)blk * chunk;
    int c = threadIdx.x & (NCOPY - 1);
    for (int i = threadIdx.x; i < chunk; i += blockDim.x) {
        float4 v = base[i];
        // (x - mn) * scale : sub then mul, no fma contraction possible
        int b0 = (int)floorf((v.x - mn) * scale);
        int b1 = (int)floorf((v.y - mn) * scale);
        int b2 = (int)floorf((v.z - mn) * scale);
        int b3 = (int)floorf((v.w - mn) * scale);
        b0 = min(max(b0, 0), NBINS - 1);
        b1 = min(max(b1, 0), NBINS - 1);
        b2 = min(max(b2, 0), NBINS - 1);
        b3 = min(max(b3, 0), NBINS - 1);
        atomicAdd(&sh[b0 * NCOPY + c], 1u);
        atomicAdd(&sh[b1 * NCOPY + c], 1u);
        atomicAdd(&sh[b2 * NCOPY + c], 1u);
        atomicAdd(&sh[b3 * NCOPY + c], 1u);
    }
    __syncthreads();
    // blockDim == 256 == NBINS: thread t owns bin t. Staggered copy index keeps 2 lanes/bank.
    int bin = threadIdx.x;
    unsigned sum = 0;
    #pragma unroll
    for (int k = 0; k < NCOPY; k++) {
        int cc = (k + threadIdx.x) & (NCOPY - 1);
        sum += sh[bin * NCOPY + cc];
    }
    partial[(long)blockIdx.x * NBINS + bin] = sum; // plain store, no init required
}

// One block per image: parallel integer bin-sum (order-free), then thread 0 does
// the sequential fp32 scan exactly mirroring np.cumsum order.
__global__ void k_otsu(const unsigned* __restrict__ partial, const unsigned* __restrict__ mmo,
                       float* __restrict__ thresh) {
    __shared__ unsigned h[NBINS];
    int img = blockIdx.x;
    int bin = threadIdx.x;
    const unsigned* p = partial + (long)img * BLK_PER_IMG * NBINS;
    unsigned sum = 0;
    #pragma unroll
    for (int k = 0; k < BLK_PER_IMG; k++) sum += p[k * NBINS + bin];
    h[bin] = sum;
    __syncthreads();
    if (threadIdx.x != 0) return;
    const float inv_total = 1.0f / 1048576.0f; // exact 2^-20; p exact (counts <= 2^20)
    float w = 0.0f, s = 0.0f;
    for (int t = 0; t < NBINS; t++) {
        float pp = __fmul_rn((float)h[t], inv_total);
        w = __fadd_rn(w, pp);
        s = __fadd_rn(s, __fmul_rn(pp, (float)t));
    }
    float total = s;
    float best = -__builtin_inff();
    int bestt = 0;
    w = 0.0f; s = 0.0f;
    for (int t = 0; t < NBINS; t++) {
        float pp = __fmul_rn((float)h[t], inv_total);
        w = __fadd_rn(w, pp);
        s = __fadd_rn(s, __fmul_rn(pp, (float)t));
        float wf = __fsub_rn(1.0f, w);
        float var;
        if (w > 0.0f && wf > 0.0f) {
            float mb = __fdiv_rn(s, w);
            float mf = __fdiv_rn(__fsub_rn(total, s), wf);
            float d = __fsub_rn(mb, mf);
            var = __fmul_rn(__fmul_rn(w, wf), __fmul_rn(d, d));
        } else {
            var = -__builtin_inff();
        }
        if (var > best) { best = var; bestt = t; }
    }
    float mn = dec_f(mmo[0]);
    float mx = dec_f(mmo[1]);
    float span = __fsub_rn(mx, mn);
    float q = __fmul_rn((float)(bestt + 1), 1.0f / 256.0f); // exact (pow2)
    thresh[img] = __fadd_rn(mn, __fmul_rn(span, q));        // mul then add, no fma
}

__global__ void k_apply(const float4* __restrict__ x, nfloat4* __restrict__ out,
                        const float* __restrict__ thresh, long n4) {
    long stride = (long)gridDim.x * blockDim.x;
    for (long i = (long)blockIdx.x * blockDim.x + threadIdx.x; i < n4; i += stride) {
        int img = (int)(i >> HW4_SHIFT); // wave-uniform (256 consecutive floats per wave)
        float th = thresh[img];
        float4 v = x[i];
        nfloat4 o;
        o.x = (v.x <= th) ? 0.0f : v.x;
        o.y = (v.y <= th) ? 0.0f : v.y;
        o.z = (v.z <= th) ? 0.0f : v.z;
        o.w = (v.w <= th) ? 0.0f : v.w;
        __builtin_nontemporal_store(o, &out[i]); // don't evict x from L3
    }
}

extern "C" void kernel_launch(void* const* d_in, const int* in_sizes, int n_in,
                              void* d_out, int out_size, void* d_ws, size_t ws_size,
                              hipStream_t stream) {
    const float* x = (const float*)d_in[0];
    float* out = (float*)d_out;
    long n = (long)in_sizes[0];          // 48 * 2^20
    long n4 = n >> 2;
    int nimg = (int)(n >> HW_SHIFT);     // 48

    unsigned* bmm = (unsigned*)d_ws;
    unsigned* mmo = bmm + 2 * MM_BLOCKS;
    unsigned* partial = mmo + 2;
    float* thresh = (float*)(partial + (long)nimg * BLK_PER_IMG * NBINS);

    k_minmax<<<MM_BLOCKS, 256, 0, stream>>>((const float4*)x, bmm, n4);
    k_reduce<<<1, 256, 0, stream>>>(bmm, mmo);
    k_hist<<<nimg * BLK_PER_IMG, 256, 0, stream>>>((const float4*)x, mmo, partial);
    k_otsu<<<nimg, 256, 0, stream>>>(partial, mmo, thresh);
    k_apply<<<4096, 256, 0, stream>>>((const float4*)x, (nfloat4*)out, thresh, n4);
}